// Round 6
// baseline (362.510 us; speedup 1.0000x reference)
//
#include <hip/hip_runtime.h>

// SPPoolMean v9: 512 rows x 65536 elems, 512 labels -> per-(row,label) mean
// gathered back to every position.
//
// Post-mortem chain (validated cost model):
//  - LDS atomic RMW unit is the wall: ~71 us/CU for 131072 lane-ops per
//    row-pair. Width-independent (packed trick), replication-insensitive
//    (v7), conflict counter ~half atomics / ~half gather reads (v8).
//  - VMEM random gather is ~27 us/row/CU vs ~5-7 on LDS (v8: +18 us,
//    conflicts 5.1M -> 2.66M but slower). LDS gather wins. REFUTED: v8.
//  - 2 blocks/CU run in lockstep, no implicit overlap (v5/v6). REFUTED.
//  - v4/v7 (119 us) waste ~16 us in pipeline fill/drain: P0 feeds the
//    atomic unit with only one row then barriers; P2 leaves it idle.
//
// v9: split the BLOCK, not the phases. Waves 0-7 own row0, waves 8-15 own
// row1 (tid<512 / >=512 -- wave-uniform, no divergence). Phase A: both
// groups load+scatter their own row concurrently -> the per-CU RMW unit
// gets one continuous ~71 us burst (loads, 42 us/CU, hide under it).
// One barrier + one finalize pass (each group finalizes its own 512 bins).
// Phase B: both groups gather their own row from LDS via register-banked
// labels (64 packed u32/thread, read from HBM exactly once) and store.
// Model: 71 + ~14 (LDS reads) + ~8 tail ~= 95-105 us.
//
// REGISTER CONTRACT: 64 lp regs live across the barrier + temps ~= 90
// VGPR under the 128 cap (__launch_bounds__(1024,4), 1 block/CU like v4).
// Falsifier: if it spills, WRITE_SIZE jumps above 131072 KB.
//
// Precision/overflow identical to v3-v8 (packed [sum_fixed<<9 | count],
// scale 2^10): rne err <= 0.5/1024/elem; cnt <= ~190 < 511;
// |sum_fixed| <= ~1.1e6 << 2^22. Output bit-identical.

constexpr int NUM_LABELS = 512;
constexpr int ROW_N      = 256 * 256;   // 65536
constexpr int BLOCK      = 1024;
constexpr int HALF       = 512;         // threads per row-group
constexpr int NV         = ROW_N / 4;   // 16384 vec4 groups per row
constexpr int ITER       = NV / HALF;   // 32 iterations per thread
constexpr float SCALE    = 1024.0f;

__device__ __forceinline__ unsigned pk(float x) {
  return ((unsigned)__float2int_rn(x * SCALE) << 9) + 1u;
}

__global__ __launch_bounds__(BLOCK, 4) void sppool_mean_kernel(
    const float* __restrict__ src,
    const int*   __restrict__ labels,
    float*       __restrict__ out) {
  __shared__ unsigned int acc0[NUM_LABELS];
  __shared__ unsigned int acc1[NUM_LABELS];

  const int tid = threadIdx.x;
  const int lt  = tid & (HALF - 1);        // lane within group
  const int grp = tid >> 9;                // 0: row0 (waves 0-7), 1: row1

  const long long base = (long long)(2 * blockIdx.x + grp) * ROW_N;
  const float4* s4 = (const float4*)(src + base);
  const int4*   l4 = (const int4*)(labels + base);
  float4*       o4 = (float4*)(out + base);

  unsigned int* __restrict__ acc = grp ? acc1 : acc0;

  // Packed labels: 4 labels (int4) -> 2x u32 of 16-bit halves. 64 regs,
  // live across the barrier (register contract above).
  unsigned lp[2 * ITER];

  if (tid < NUM_LABELS) { acc0[tid] = 0u; }
  else                  { acc1[lt] = 0u; }
  __syncthreads();

  // Phase A: both groups load+scatter their own row. The CU's LDS-RMW
  // unit runs one continuous burst over both rows' 131072 lane-ops;
  // global loads (1 MB/CU total) hide underneath.
  #pragma unroll
  for (int k = 0; k < ITER; ++k) {
    const int i = lt + k * HALF;
    float4 v = s4[i];
    int4   l = l4[i];
    lp[2 * k]     = (unsigned)l.x | ((unsigned)l.y << 16);
    lp[2 * k + 1] = (unsigned)l.z | ((unsigned)l.w << 16);
    atomicAdd(&acc[l.x], pk(v.x));
    atomicAdd(&acc[l.y], pk(v.y));
    atomicAdd(&acc[l.z], pk(v.z));
    atomicAdd(&acc[l.w], pk(v.w));
  }
  __syncthreads();

  // Finalize both rows in one pass: each group's 512 threads cover its
  // own 512 bins.
  {
    unsigned u = acc[lt];
    int cnt = (int)(u & 511u);
    int sf  = ((int)u) >> 9;                        // arithmetic: signed sum
    float mean = (float)sf / (SCALE * (float)cnt);  // cnt==0 -> nan, unused
    acc[lt] = __float_as_uint(mean);
  }
  __syncthreads();

  // Phase B: both groups gather their own row from LDS (labels from regs,
  // no HBM label re-read) and store.
  #pragma unroll
  for (int k = 0; k < ITER; ++k) {
    const int i = lt + k * HALF;
    const unsigned pa = lp[2 * k];
    const unsigned pb = lp[2 * k + 1];
    float4 r;
    r.x = __uint_as_float(acc[pa & 0xffffu]);
    r.y = __uint_as_float(acc[pa >> 16]);
    r.z = __uint_as_float(acc[pb & 0xffffu]);
    r.w = __uint_as_float(acc[pb >> 16]);
    o4[i] = r;
  }
}

extern "C" void kernel_launch(void* const* d_in, const int* in_sizes, int n_in,
                              void* d_out, int out_size, void* d_ws, size_t ws_size,
                              hipStream_t stream) {
  const float* src    = (const float*)d_in[0];
  const int*   labels = (const int*)d_in[1];
  float*       out    = (float*)d_out;

  const int rows = in_sizes[0] / ROW_N;  // 512
  sppool_mean_kernel<<<rows / 2, BLOCK, 0, stream>>>(src, labels, out);
}

// Round 7
// 328.586 us; speedup vs baseline: 1.1032x; 1.1032x over previous
//
#include <hip/hip_runtime.h>

// SPPoolMean v10: 512 rows x 65536 elems, 512 labels -> per-(row,label) mean
// gathered back to every position.
//
// Post-mortem chain (validated):
//  - LDS atomic RMW wall: 71 us/CU per row-pair (1.3 cyc/lane-op; width-
//    independent, replication-insensitive (v7), VMEM gather worse (v8)).
//  - REGISTER RULE: <=32 banked u32/thread across a barrier is safe (v7,
//    VGPR 56); 64 spills regardless of launch_bounds cap (v5: +55MB, v9:
//    +89MB scratch traffic). v10 banks NOTHING.
//  - 2 blocks/CU co-residency is lockstep-harmful (v5/v6). v10 pins
//    1 block/CU with a 96KB LDS pad (static 100KB LDS is gfx950-proven).
//  - v7 (119us) = 85us LDS-pipe floor + ~34us structure overhead (exposed
//    P2 tail, barrier drains, mixed-loop latency stalls).
//
// v10 = producer/consumer wave specialization (1 block/CU, 2 rows):
//  P0: waves 0-7 (S) scatter row0 (atomic 35.5us; loads hide under it).
//  P1: S scatters row1 under s_setprio(1) WHILE waves 8-15 (G) gather
//      row0 -- G re-reads labels (L2/L3-hot from P0) so no reg banking.
//      P1 wall = LDS 35.5 atomic + 7 gather = 42.5us; mem 36us hidden.
//  P2: ALL 16 waves gather row1 (labels L2-hot from P1): ~15us tail.
//  Model ~= 98us vs v7's 119.
//
// Falsifiers: WRITE_SIZE exactly 131072 KB; LDS_Block_Size ~102KB;
// dur >= 119 => specialization null => structural floor reached.
//
// Precision/overflow identical to v3-v9 (packed [sum_fixed<<9 | count],
// scale 2^10): rne err <= 0.5/1024/elem; cnt <= ~190 < 511;
// |sum_fixed| <= ~1.1e6 << 2^22. Output bit-identical.

constexpr int NUM_LABELS = 512;
constexpr int ROW_N      = 256 * 256;   // 65536
constexpr int BLOCK      = 1024;
constexpr int HALF       = 512;         // threads per role group
constexpr int NV         = ROW_N / 4;   // 16384 vec4 groups per row
constexpr int ITER_H     = NV / HALF;   // 32 iters (half-block loops)
constexpr int ITER_A     = NV / BLOCK;  // 16 iters (all-block loop)
constexpr float SCALE    = 1024.0f;

__device__ __forceinline__ unsigned pk(float x) {
  return ((unsigned)__float2int_rn(x * SCALE) << 9) + 1u;
}

__device__ __forceinline__ void finalize_means(unsigned int* __restrict__ a,
                                               int t) {
  unsigned u = a[t];
  int cnt = (int)(u & 511u);
  int sf  = ((int)u) >> 9;                        // arithmetic: signed sum
  float mean = (float)sf / (SCALE * (float)cnt);  // cnt==0 -> nan, unused
  a[t] = __float_as_uint(mean);
}

__global__ __launch_bounds__(BLOCK, 4) void sppool_mean_kernel(
    const float* __restrict__ src,
    const int*   __restrict__ labels,
    float*       __restrict__ out) {
  __shared__ unsigned int acc0[NUM_LABELS];
  __shared__ unsigned int acc1[NUM_LABELS];
  // 96 KB pad -> static LDS 100 KB/block -> hardware can place only ONE
  // block per CU (160 KB pool). Guarded touch keeps it allocated; src is
  // a runtime arg so the branch cannot be folded away.
  __shared__ unsigned int lds_pad[24576];

  const int tid = threadIdx.x;
  if (src == nullptr) {               // never true at runtime
    lds_pad[tid] = (unsigned)tid;
    out[tid] = (float)lds_pad[tid ^ 1];
  }

  const int lt  = tid & (HALF - 1);   // lane within role group
  const int grp = tid >> 9;           // 0 = S (scatter), 1 = G (gather)

  const long long base0 = (long long)(2 * blockIdx.x) * ROW_N;
  const float4* s0 = (const float4*)(src + base0);
  const int4*   l0 = (const int4*)(labels + base0);
  float4*       o0 = (float4*)(out + base0);
  const float4* s1 = s0 + NV;
  const int4*   l1 = l0 + NV;
  float4*       o1 = o0 + NV;

  if (tid < NUM_LABELS) { acc0[tid] = 0u; }
  else                  { acc1[lt] = 0u; }
  __syncthreads();

  // P0: S scatters row0 (pure atomic burst; loads hide under the 35.5us
  // atomic wall). G idles at the barrier -- no issue slots consumed.
  if (grp == 0) {
    for (int k = 0; k < ITER_H; ++k) {
      const int i = lt + k * HALF;
      float4 v = s0[i];
      int4   l = l0[i];
      atomicAdd(&acc0[l.x], pk(v.x));
      atomicAdd(&acc0[l.y], pk(v.y));
      atomicAdd(&acc0[l.z], pk(v.z));
      atomicAdd(&acc0[l.w], pk(v.w));
    }
  }
  __syncthreads();

  if (tid < NUM_LABELS) finalize_means(acc0, tid);
  __syncthreads();

  // P1: role split. S scatters row1 with raised priority (atomic stream is
  // the critical 35.5us; G's ds_reads fit in its slack). G gathers row0,
  // re-reading labels (L2/L3-hot from P0) -- no register banking anywhere.
  if (grp == 0) {
    __builtin_amdgcn_s_setprio(1);
    for (int k = 0; k < ITER_H; ++k) {
      const int i = lt + k * HALF;
      float4 v = s1[i];
      int4   l = l1[i];
      atomicAdd(&acc1[l.x], pk(v.x));
      atomicAdd(&acc1[l.y], pk(v.y));
      atomicAdd(&acc1[l.z], pk(v.z));
      atomicAdd(&acc1[l.w], pk(v.w));
    }
    __builtin_amdgcn_s_setprio(0);
  } else {
    for (int k = 0; k < ITER_H; ++k) {
      const int i = lt + k * HALF;
      int4 l = l0[i];
      float4 r;
      r.x = __uint_as_float(acc0[l.x]);
      r.y = __uint_as_float(acc0[l.y]);
      r.z = __uint_as_float(acc0[l.z]);
      r.w = __uint_as_float(acc0[l.w]);
      o0[i] = r;
    }
  }
  __syncthreads();

  if (tid < NUM_LABELS) finalize_means(acc1, tid);
  __syncthreads();

  // P2: all 16 waves gather row1 (labels L2-hot from P1's scatter read).
  for (int k = 0; k < ITER_A; ++k) {
    const int i = tid + k * BLOCK;
    int4 l = l1[i];
    float4 r;
    r.x = __uint_as_float(acc1[l.x]);
    r.y = __uint_as_float(acc1[l.y]);
    r.z = __uint_as_float(acc1[l.z]);
    r.w = __uint_as_float(acc1[l.w]);
    o1[i] = r;
  }
}

extern "C" void kernel_launch(void* const* d_in, const int* in_sizes, int n_in,
                              void* d_out, int out_size, void* d_ws, size_t ws_size,
                              hipStream_t stream) {
  const float* src    = (const float*)d_in[0];
  const int*   labels = (const int*)d_in[1];
  float*       out    = (float*)d_out;

  const int rows = in_sizes[0] / ROW_N;  // 512
  sppool_mean_kernel<<<rows / 2, BLOCK, 0, stream>>>(src, labels, out);
}